// Round 6
// baseline (457.129 us; speedup 1.0000x reference)
//
#include <hip/hip_runtime.h>
#include <math.h>

#define Bn 8
#define Cn 10
#define Hd 384
#define Wd 384
#define HW (Hd*Wd)          // 147456
#define TX 32
#define TY 8
#define TLX 36              // TX + 4 halo
#define TLY 12              // TY + 4 halo
#define TSZ (TLX*TLY)       // 432
#define BLOCKS_PER_IMG 576  // HW/256
#define TILES_X 12          // 384/32

typedef __attribute__((ext_vector_type(8))) short s8v;   // 8 x bf16 (4 VGPRs)
typedef __attribute__((ext_vector_type(4))) float f4v;   // MFMA C/D

__device__ __forceinline__ unsigned short f2bf(float f) {
    unsigned u = __builtin_bit_cast(unsigned, f);
    u += 0x7fffu + ((u >> 16) & 1u);           // RNE (values are finite)
    return (unsigned short)(u >> 16);
}

// Branchless erf-GELU, Abramowitz-Stegun 7.1.26 (|err| <= 1.5e-7)
__device__ __forceinline__ float gelu_erf(float h) {
    float z  = 0.70710678118654752f * h;
    float az = fabsf(z);
    float t  = __builtin_amdgcn_rcpf(1.0f + 0.3275911f * az);
    float poly = ((((1.061405429f * t - 1.453152027f) * t + 1.421413741f) * t
                   - 0.284496736f) * t + 0.254829592f) * t;
    float e = __expf(-az * az);
    float erf_z = copysignf(1.0f - poly * e, z);
    return 0.5f * h * (1.0f + erf_z);
}

// ---------------- Kernel A: softmax + neighborhood features ----------------
// CHANNEL-MAJOR LDS (reverted: pixel-major b128 variants cost +20us in
// R2/R5 bundles). 11 planes: P0..P9 plus U = sum_c P^2. The U plane replaces
// the per-channel square accumulators: var = boxsum(U)/K - sum((S/K)^2),
// match = sum_c pc*S_c - Uc. Same-layout, strict instruction-count cut
// (~500 FMA/thread -> 25 b32 reads + 50 adds/thread).
__global__ __launch_bounds__(256) void kA(const float* __restrict__ x,
                                          float* __restrict__ fout) {
    __shared__ float Pt[(Cn + 1) * TSZ];
    const int bid = blockIdx.x;
    const int b   = bid / BLOCKS_PER_IMG;
    const int t   = bid % BLOCKS_PER_IMG;
    const int ty  = t / TILES_X, tx = t % TILES_X;
    const int x0  = tx * TX, y0 = ty * TY;
    const int tid = threadIdx.x;
    const float* xb = x + (size_t)b * Cn * HW;

    for (int i = tid; i < TSZ; i += 256) {
        int ly = i / TLX, lx = i % TLX;
        int gy = y0 + ly - 2; gy = max(0, min(Hd - 1, gy));
        int gx = x0 + lx - 2; gx = max(0, min(Wd - 1, gx));
        const float* px = xb + gy * Wd + gx;
        float v[Cn];
        float m = -1e30f;
        #pragma unroll
        for (int c = 0; c < Cn; c++) { v[c] = px[c * HW]; m = fmaxf(m, v[c]); }
        float s = 0.f;
        #pragma unroll
        for (int c = 0; c < Cn; c++) { v[c] = __expf(v[c] - m); s += v[c]; }
        float inv = 1.0f / s;
        float U = 0.f;
        #pragma unroll
        for (int c = 0; c < Cn; c++) {
            float p = v[c] * inv;
            Pt[c * TSZ + i] = p;
            U += p * p;
        }
        Pt[Cn * TSZ + i] = U;
    }
    __syncthreads();

    const int lx = tid % TX, ly = tid / TX;
    const int ctr = (ly + 2) * TLX + (lx + 2);

    float dot3 = 0.f, dot5 = 0.f, maj3 = -1e30f, maj5 = -1e30f;
    float ent3 = 0.f, ent5 = 0.f, sq3 = 0.f, sq5 = 0.f;

    #pragma unroll 1
    for (int c = 0; c < Cn; c++) {
        const float* Pc = &Pt[c * TSZ + ctr];
        float S5 = 0.f, S3 = 0.f;
        #pragma unroll
        for (int dy = -2; dy <= 2; dy++) {
            #pragma unroll
            for (int dx = -2; dx <= 2; dx++) {
                float v = Pc[dy * TLX + dx];
                S5 += v;
                if (dy >= -1 && dy <= 1 && dx >= -1 && dx <= 1) S3 += v;
            }
        }
        float pc = Pc[0];
        dot3 += pc * S3;
        dot5 += pc * S5;
        maj3 = fmaxf(maj3, S3);
        maj5 = fmaxf(maj5, S5);
        float q3 = fmaxf(S3 * (1.f / 9.f), 1e-8f);  ent3 -= q3 * __logf(q3);
        float q5 = fmaxf(S5 * (1.f / 25.f), 1e-8f); ent5 -= q5 * __logf(q5);
        float pb3 = S3 * (1.f / 9.f);  sq3 += pb3 * pb3;
        float pb5 = S5 * (1.f / 25.f); sq5 += pb5 * pb5;
    }

    // U-plane box sums (replaces per-channel Q accumulation)
    float U5 = 0.f, U3 = 0.f, Uc;
    {
        const float* Pu = &Pt[Cn * TSZ + ctr];
        #pragma unroll
        for (int dy = -2; dy <= 2; dy++) {
            #pragma unroll
            for (int dx = -2; dx <= 2; dx++) {
                float u = Pu[dy * TLX + dx];
                U5 += u;
                if (dy >= -1 && dy <= 1 && dx >= -1 && dx <= 1) U3 += u;
            }
        }
        Uc = Pu[0];
    }

    const float invlogC = 1.0f / 2.302585092994046f;
    float f0 = (dot3 - Uc) * (1.f / 8.f);
    float f1 = maj3 * (1.f / 9.f);
    float f2 = 1.f - ent3 * invlogC;
    float f3 = U3 * (1.f / 9.f) - sq3;
    float f4 = (dot5 - Uc) * (1.f / 24.f);
    float f5 = maj5 * (1.f / 25.f);
    float f6 = 1.f - ent5 * invlogC;
    float f7 = U5 * (1.f / 25.f) - sq5;

    int p = b * HW + (y0 + ly) * Wd + (x0 + lx);
    float4* o = (float4*)(fout + (size_t)p * 8);
    o[0] = make_float4(f0, f1, f2, f3);
    o[1] = make_float4(f4, f5, f6, f7);
}

// ---------------- Kernel A2: per-batch moments of f (8 + 36) ----------------
// 576 blocks (72/batch, 2048 px each) -> full-GPU occupancy.
__global__ __launch_bounds__(256) void kA2(const float* __restrict__ f,
                                           double* __restrict__ stats) {
    const int blk = blockIdx.x;
    const int b = blk / 72, sub = blk % 72;
    const int base = b * HW + sub * 2048;
    const int tid = threadIdx.x;

    float s[8];
    float q[36];
    #pragma unroll
    for (int i = 0; i < 8; i++) s[i] = 0.f;
    #pragma unroll
    for (int i = 0; i < 36; i++) q[i] = 0.f;

    for (int j = 0; j < 8; j++) {
        int p = base + j * 256 + tid;
        const float4* fv = (const float4*)(f + (size_t)p * 8);
        float4 a = fv[0], c4 = fv[1];
        float fl[8] = {a.x, a.y, a.z, a.w, c4.x, c4.y, c4.z, c4.w};
        int idx = 0;
        #pragma unroll
        for (int c = 0; c < 8; c++) {
            s[c] += fl[c];
            #pragma unroll
            for (int cp = c; cp < 8; cp++) { q[idx] += fl[c] * fl[cp]; idx++; }
        }
    }

    #pragma unroll
    for (int c = 0; c < 8; c++)
        for (int o = 32; o >= 1; o >>= 1) s[c] += __shfl_xor(s[c], o);
    #pragma unroll
    for (int i = 0; i < 36; i++)
        for (int o = 32; o >= 1; o >>= 1) q[i] += __shfl_xor(q[i], o);

    __shared__ float red[4][44];
    int lane = tid & 63, wv = tid >> 6;
    if (lane == 0) {
        #pragma unroll
        for (int c = 0; c < 8; c++) red[wv][c] = s[c];
        #pragma unroll
        for (int i = 0; i < 36; i++) red[wv][8 + i] = q[i];
    }
    __syncthreads();
    if (tid < 44) {
        float tot = red[0][tid] + red[1][tid] + red[2][tid] + red[3][tid];
        atomicAdd(&stats[b * 44 + tid], (double)tot);
    }
}

// ---------------- Kernel B: analytic GroupNorm scale/shift ----------------
__global__ __launch_bounds__(512) void kB(const double* __restrict__ stats,
                                          const float* __restrict__ W1,
                                          const float* __restrict__ b1,
                                          const float* __restrict__ gnw,
                                          const float* __restrict__ gnb,
                                          float* __restrict__ ga,
                                          float* __restrict__ gb) {
    const int tid = threadIdx.x;
    const int b = tid >> 6, d = tid & 63;
    const double* st = stats + b * 44;
    const double invN = 1.0 / (double)HW;

    double m[8];
    #pragma unroll
    for (int c = 0; c < 8; c++) m[c] = st[c] * invN;
    double w[8];
    #pragma unroll
    for (int c = 0; c < 8; c++) w[c] = (double)W1[d * 8 + c];

    double wv = 0.0;
    #pragma unroll
    for (int c = 0; c < 8; c++) wv += w[c] * m[c];

    double quad = 0.0;
    int idx = 8;
    #pragma unroll
    for (int c = 0; c < 8; c++) {
        #pragma unroll
        for (int cp = c; cp < 8; cp++) {
            double e2 = st[idx] * invN; idx++;
            quad += (c == cp ? 1.0 : 2.0) * w[c] * w[cp] * e2;
        }
    }
    double bb  = (double)b1[d];
    double mu  = wv + bb;
    double eh2 = quad + 2.0 * bb * wv + bb * bb;

    double gm = mu, gq = eh2;
    #pragma unroll
    for (int o = 1; o < 8; o <<= 1) { gm += __shfl_xor(gm, o); gq += __shfl_xor(gq, o); }
    gm *= 0.125; gq *= 0.125;
    double var = gq - gm * gm;
    double rs  = rsqrt(var + 1e-5);

    float A  = (float)rs * gnw[d];
    float Bs = gnb[d] - (float)(gm * rs) * gnw[d];
    ga[tid] = A;
    gb[tid] = Bs;
}

// ------- Kernel C2: 1x1conv -> GN affine -> GELU -> MFMA 1x1conv -----------
// Block = 256 threads = 4 waves = 256 pixels. Layer2 via 16x16x32 bf16 MFMA
// with SWAPPED operands: D[px][e] = sum_k g[k][px] * W2^T[k][e], so each
// lane's 4 acc regs are 4 consecutive px of one e row -> global_store_dwordx4
// (16 store instrs/thread instead of 64; same 64B/row segments).
__global__ __launch_bounds__(256) void kC2(const float* __restrict__ f,
                                           const float* __restrict__ W1,
                                           const float* __restrict__ b1,
                                           const float* __restrict__ W2,
                                           const float* __restrict__ b2,
                                           const float* __restrict__ ga,
                                           const float* __restrict__ gb,
                                           float* __restrict__ out) {
    __shared__ unsigned gl[256 * 33];
    const int b    = blockIdx.x / BLOCKS_PER_IMG;
    const int tile = blockIdx.x % BLOCKS_PER_IMG;
    const int pix0 = tile * 256;
    const int tid  = threadIdx.x;

    // ---- phase 1: per-thread pixel -> h[64] -> GN affine -> GELU -> LDS ----
    {
        const float4* fv = (const float4*)(f + ((size_t)(b * HW + pix0 + tid)) * 8);
        float4 A = fv[0], Bv = fv[1];
        float fl[8] = {A.x, A.y, A.z, A.w, Bv.x, Bv.y, Bv.z, Bv.w};
        const float* gaB = ga + b * 64;
        const float* gbB = gb + b * 64;
        unsigned* row = &gl[tid * 33];
        #pragma unroll
        for (int d2 = 0; d2 < 32; d2++) {
            float h0 = b1[2 * d2], h1 = b1[2 * d2 + 1];
            #pragma unroll
            for (int c = 0; c < 8; c++) {
                h0 += W1[(2 * d2) * 8 + c] * fl[c];
                h1 += W1[(2 * d2 + 1) * 8 + c] * fl[c];
            }
            h0 = h0 * gaB[2 * d2]     + gbB[2 * d2];
            h1 = h1 * gaB[2 * d2 + 1] + gbB[2 * d2 + 1];
            float g0 = gelu_erf(h0), g1 = gelu_erf(h1);
            unsigned pk;
            asm("v_cvt_pk_bf16_f32 %0, %1, %2" : "=v"(pk) : "v"(g0), "v"(g1));
            row[d2] = pk;
        }
    }
    __syncthreads();

    // ---- phase 2: D[px][e] via MFMA (swapped operands) ----
    const int w    = tid >> 6;
    const int lane = tid & 63;
    const int quad = lane >> 4;
    const int col  = lane & 15;

    // W2 fragments (B operand): B[k][n=col] = W2[16u+col][kc*32+quad*8+j]
    s8v wfr[4][2];
    #pragma unroll
    for (int u = 0; u < 4; u++) {
        const float* wr = W2 + (size_t)(16 * u + col) * 64 + quad * 8;
        #pragma unroll
        for (int kc = 0; kc < 2; kc++) {
            const float4* w4 = (const float4*)(wr + 32 * kc);
            float4 x0 = w4[0], x1 = w4[1];
            union { unsigned short us[8]; s8v v; } cv;
            cv.us[0] = f2bf(x0.x); cv.us[1] = f2bf(x0.y);
            cv.us[2] = f2bf(x0.z); cv.us[3] = f2bf(x0.w);
            cv.us[4] = f2bf(x1.x); cv.us[5] = f2bf(x1.y);
            cv.us[6] = f2bf(x1.z); cv.us[7] = f2bf(x1.w);
            wfr[u][kc] = cv.v;
        }
    }

    // acc2[t][u]: rows px = 64w+16t+quad*4+r, col e = 16u+col; init with b2[e]
    f4v acc2[4][4];
    #pragma unroll
    for (int u = 0; u < 4; u++) {
        float bv = b2[16 * u + col];
        #pragma unroll
        for (int t = 0; t < 4; t++) {
            f4v a0; a0[0] = bv; a0[1] = bv; a0[2] = bv; a0[3] = bv;
            acc2[t][u] = a0;
        }
    }

    #pragma unroll
    for (int kc = 0; kc < 2; kc++) {
        s8v gfr[4];
        #pragma unroll
        for (int t = 0; t < 4; t++) {
            int px = 64 * w + 16 * t + col;
            const unsigned* r = &gl[px * 33 + kc * 16 + quad * 4];
            union { unsigned u4[4]; s8v v; } cv;
            cv.u4[0] = r[0]; cv.u4[1] = r[1]; cv.u4[2] = r[2]; cv.u4[3] = r[3];
            gfr[t] = cv.v;
        }
        #pragma unroll
        for (int u = 0; u < 4; u++)
            #pragma unroll
            for (int t = 0; t < 4; t++)
                acc2[t][u] = __builtin_amdgcn_mfma_f32_16x16x32_bf16(
                    gfr[t], wfr[u][kc], acc2[t][u], 0, 0, 0);
    }

    // ---- store: float4 of 4 consecutive px per (u,t) ----
    float* ob = out + (size_t)b * 64 * HW + pix0;
    #pragma unroll
    for (int u = 0; u < 4; u++) {
        float* oe = ob + (size_t)(16 * u + col) * HW + 64 * w + quad * 4;
        #pragma unroll
        for (int t = 0; t < 4; t++) {
            float4 sv = make_float4(acc2[t][u][0], acc2[t][u][1],
                                    acc2[t][u][2], acc2[t][u][3]);
            *(float4*)(oe + 16 * t) = sv;
        }
    }
}

extern "C" void kernel_launch(void* const* d_in, const int* in_sizes, int n_in,
                              void* d_out, int out_size, void* d_ws, size_t ws_size,
                              hipStream_t stream) {
    const float* x   = (const float*)d_in[0];
    const float* W1  = (const float*)d_in[1];
    const float* b1  = (const float*)d_in[2];
    const float* gnw = (const float*)d_in[3];
    const float* gnb = (const float*)d_in[4];
    const float* W2  = (const float*)d_in[5];
    const float* b2  = (const float*)d_in[6];
    float* out = (float*)d_out;

    char* ws = (char*)d_ws;
    const size_t FBYTES = (size_t)Bn * HW * 8 * sizeof(float); // 37,748,736
    float*  fbuf  = (float*)ws;
    double* stats = (double*)(ws + FBYTES);
    float*  ga    = (float*)(ws + FBYTES + 8 * 44 * sizeof(double));
    float*  gbuf  = ga + Bn * 64;

    hipMemsetAsync(stats, 0, 8 * 44 * sizeof(double), stream);
    kA<<<Bn * BLOCKS_PER_IMG, 256, 0, stream>>>(x, fbuf);
    kA2<<<576, 256, 0, stream>>>(fbuf, stats);
    kB<<<1, 512, 0, stream>>>(stats, W1, b1, gnw, gnb, ga, gbuf);
    kC2<<<Bn * BLOCKS_PER_IMG, 256, 0, stream>>>(fbuf, W1, b1, W2, b2, ga, gbuf, out);
}

// Round 8
// 430.834 us; speedup vs baseline: 1.0610x; 1.0610x over previous
//
#include <hip/hip_runtime.h>
#include <math.h>

#define Bn 8
#define Cn 10
#define Hd 384
#define Wd 384
#define HW (Hd*Wd)          // 147456
#define TX 32
#define TY 8
#define TLX 36              // TX + 4 halo
#define TLY 12              // TY + 4 halo
#define TSZ (TLX*TLY)       // 432
#define BLOCKS_PER_IMG 576  // HW/256
#define TILES_X 12          // 384/32

typedef __attribute__((ext_vector_type(8))) short s8v;   // 8 x bf16 (4 VGPRs)
typedef __attribute__((ext_vector_type(4))) float f4v;   // MFMA C/D

__device__ __forceinline__ unsigned short f2bf(float f) {
    unsigned u = __builtin_bit_cast(unsigned, f);
    u += 0x7fffu + ((u >> 16) & 1u);           // RNE (values are finite)
    return (unsigned short)(u >> 16);
}

// Branchless erf-GELU, Abramowitz-Stegun 7.1.26 (|err| <= 1.5e-7)
__device__ __forceinline__ float gelu_erf(float h) {
    float z  = 0.70710678118654752f * h;
    float az = fabsf(z);
    float t  = __builtin_amdgcn_rcpf(1.0f + 0.3275911f * az);
    float poly = ((((1.061405429f * t - 1.453152027f) * t + 1.421413741f) * t
                   - 0.284496736f) * t + 0.254829592f) * t;
    float e = __expf(-az * az);
    float erf_z = copysignf(1.0f - poly * e, z);
    return 0.5f * h * (1.0f + erf_z);
}

// ---------------- Kernel A: softmax + neighborhood features ----------------
// EXACT 426us-baseline version (channel-major LDS, unroll-1 channel loop).
// R2/R5/R6 established all kA re-layouts are neutral-to-negative.
__global__ __launch_bounds__(256) void kA(const float* __restrict__ x,
                                          float* __restrict__ fout) {
    __shared__ float Pt[Cn * TSZ];
    const int bid = blockIdx.x;
    const int b   = bid / BLOCKS_PER_IMG;
    const int t   = bid % BLOCKS_PER_IMG;
    const int ty  = t / TILES_X, tx = t % TILES_X;
    const int x0  = tx * TX, y0 = ty * TY;
    const int tid = threadIdx.x;
    const float* xb = x + b * Cn * HW;

    for (int i = tid; i < TSZ; i += 256) {
        int ly = i / TLX, lx = i % TLX;
        int gy = y0 + ly - 2; gy = max(0, min(Hd - 1, gy));
        int gx = x0 + lx - 2; gx = max(0, min(Wd - 1, gx));
        const float* px = xb + gy * Wd + gx;
        float v[Cn];
        float m = -1e30f;
        #pragma unroll
        for (int c = 0; c < Cn; c++) { v[c] = px[c * HW]; m = fmaxf(m, v[c]); }
        float s = 0.f;
        #pragma unroll
        for (int c = 0; c < Cn; c++) { v[c] = __expf(v[c] - m); s += v[c]; }
        float inv = 1.0f / s;
        #pragma unroll
        for (int c = 0; c < Cn; c++) Pt[c * TSZ + i] = v[c] * inv;
    }
    __syncthreads();

    const int lx = tid % TX, ly = tid / TX;
    float match3 = 0.f, ent3 = 0.f, var3 = 0.f, maj3 = -1e30f;
    float match5 = 0.f, ent5 = 0.f, var5 = 0.f, maj5 = -1e30f;

    #pragma unroll 1
    for (int c = 0; c < Cn; c++) {
        const float* Pc = &Pt[c * TSZ + (ly + 2) * TLX + (lx + 2)];
        float S5 = 0.f, S3 = 0.f, Q5 = 0.f, Q3 = 0.f;
        #pragma unroll
        for (int dy = -2; dy <= 2; dy++) {
            #pragma unroll
            for (int dx = -2; dx <= 2; dx++) {
                float v = Pc[dy * TLX + dx];
                S5 += v; Q5 += v * v;
                if (dy >= -1 && dy <= 1 && dx >= -1 && dx <= 1) {
                    S3 += v; Q3 += v * v;
                }
            }
        }
        float pc = Pc[0];
        match3 += pc * (S3 - pc);
        match5 += pc * (S5 - pc);
        maj3 = fmaxf(maj3, S3);
        maj5 = fmaxf(maj5, S5);
        float q3 = fmaxf(S3 * (1.f / 9.f), 1e-8f);  ent3 -= q3 * __logf(q3);
        float q5 = fmaxf(S5 * (1.f / 25.f), 1e-8f); ent5 -= q5 * __logf(q5);
        float pb3 = S3 * (1.f / 9.f);  var3 += Q3 * (1.f / 9.f)  - pb3 * pb3;
        float pb5 = S5 * (1.f / 25.f); var5 += Q5 * (1.f / 25.f) - pb5 * pb5;
    }

    const float invlogC = 1.0f / 2.302585092994046f;
    float f0 = match3 * (1.f / 8.f);
    float f1 = maj3 * (1.f / 9.f);
    float f2 = 1.f - ent3 * invlogC;
    float f3 = var3;
    float f4 = match5 * (1.f / 24.f);
    float f5 = maj5 * (1.f / 25.f);
    float f6 = 1.f - ent5 * invlogC;
    float f7 = var5;

    int p = b * HW + (y0 + ly) * Wd + (x0 + lx);
    float4* o = (float4*)(fout + (size_t)p * 8);
    o[0] = make_float4(f0, f1, f2, f3);
    o[1] = make_float4(f4, f5, f6, f7);
}

// ---------------- Kernel A2: per-batch moments of f (8 + 36) ----------------
// EXACT baseline version (72 blocks, 64 px-iters each).
__global__ __launch_bounds__(256) void kA2(const float* __restrict__ f,
                                           double* __restrict__ stats) {
    const int blk = blockIdx.x;
    const int b = blk / 9, sub = blk % 9;
    const int base = b * HW + sub * 16384;
    const int tid = threadIdx.x;

    float s[8];
    float q[36];
    #pragma unroll
    for (int i = 0; i < 8; i++) s[i] = 0.f;
    #pragma unroll
    for (int i = 0; i < 36; i++) q[i] = 0.f;

    for (int j = 0; j < 64; j++) {
        int p = base + j * 256 + tid;
        const float4* fv = (const float4*)(f + (size_t)p * 8);
        float4 a = fv[0], c4 = fv[1];
        float fl[8] = {a.x, a.y, a.z, a.w, c4.x, c4.y, c4.z, c4.w};
        int idx = 0;
        #pragma unroll
        for (int c = 0; c < 8; c++) {
            s[c] += fl[c];
            #pragma unroll
            for (int cp = c; cp < 8; cp++) { q[idx] += fl[c] * fl[cp]; idx++; }
        }
    }

    #pragma unroll
    for (int c = 0; c < 8; c++)
        for (int o = 32; o >= 1; o >>= 1) s[c] += __shfl_xor(s[c], o);
    #pragma unroll
    for (int i = 0; i < 36; i++)
        for (int o = 32; o >= 1; o >>= 1) q[i] += __shfl_xor(q[i], o);

    __shared__ float red[4][44];
    int lane = tid & 63, wv = tid >> 6;
    if (lane == 0) {
        #pragma unroll
        for (int c = 0; c < 8; c++) red[wv][c] = s[c];
        #pragma unroll
        for (int i = 0; i < 36; i++) red[wv][8 + i] = q[i];
    }
    __syncthreads();
    if (tid < 44) {
        float tot = red[0][tid] + red[1][tid] + red[2][tid] + red[3][tid];
        atomicAdd(&stats[b * 44 + tid], (double)tot);
    }
}

// ---------------- Kernel B: analytic GroupNorm scale/shift ----------------
__global__ __launch_bounds__(512) void kB(const double* __restrict__ stats,
                                          const float* __restrict__ W1,
                                          const float* __restrict__ b1,
                                          const float* __restrict__ gnw,
                                          const float* __restrict__ gnb,
                                          float* __restrict__ ga,
                                          float* __restrict__ gb) {
    const int tid = threadIdx.x;
    const int b = tid >> 6, d = tid & 63;
    const double* st = stats + b * 44;
    const double invN = 1.0 / (double)HW;

    double m[8];
    #pragma unroll
    for (int c = 0; c < 8; c++) m[c] = st[c] * invN;
    double w[8];
    #pragma unroll
    for (int c = 0; c < 8; c++) w[c] = (double)W1[d * 8 + c];

    double wv = 0.0;
    #pragma unroll
    for (int c = 0; c < 8; c++) wv += w[c] * m[c];

    double quad = 0.0;
    int idx = 8;
    #pragma unroll
    for (int c = 0; c < 8; c++) {
        #pragma unroll
        for (int cp = c; cp < 8; cp++) {
            double e2 = st[idx] * invN; idx++;
            quad += (c == cp ? 1.0 : 2.0) * w[c] * w[cp] * e2;
        }
    }
    double bb  = (double)b1[d];
    double mu  = wv + bb;
    double eh2 = quad + 2.0 * bb * wv + bb * bb;

    double gm = mu, gq = eh2;
    #pragma unroll
    for (int o = 1; o < 8; o <<= 1) { gm += __shfl_xor(gm, o); gq += __shfl_xor(gq, o); }
    gm *= 0.125; gq *= 0.125;
    double var = gq - gm * gm;
    double rs  = rsqrt(var + 1e-5);

    float A  = (float)rs * gnw[d];
    float Bs = gnb[d] - (float)(gm * rs) * gnw[d];
    ga[tid] = A;
    gb[tid] = Bs;
}

// ------- Kernel C2: 1x1conv -> GN affine -> GELU -> MFMA 1x1conv -----------
// ONLY changed kernel vs the 426us baseline. Two deltas:
// (1) SWAPPED MFMA operands: D[px][e] = sum_k g[k][px]*W2^T[k][e] -> lane's
//     4 acc regs are 4 consecutive px of one e row -> 16x global_store_dwordx4
//     instead of 64 scalar stores (identical 64B-segment set to HBM).
// (2) bf16 pack via integer f2bf (asm v_cvt_pk_bf16_f32 REMOVED -- guide T12
//     measured inline-asm cvt_pk -37% vs scalar path; prime suspect for the
//     R2/R5/R6 bundle regressions).
__global__ __launch_bounds__(256) void kC2(const float* __restrict__ f,
                                           const float* __restrict__ W1,
                                           const float* __restrict__ b1,
                                           const float* __restrict__ W2,
                                           const float* __restrict__ b2,
                                           const float* __restrict__ ga,
                                           const float* __restrict__ gb,
                                           float* __restrict__ out) {
    __shared__ unsigned gl[256 * 33];
    const int b    = blockIdx.x / BLOCKS_PER_IMG;
    const int tile = blockIdx.x % BLOCKS_PER_IMG;
    const int pix0 = tile * 256;
    const int tid  = threadIdx.x;

    // ---- phase 1: per-thread pixel -> h[64] -> GN affine -> GELU -> LDS ----
    {
        const float4* fv = (const float4*)(f + ((size_t)(b * HW + pix0 + tid)) * 8);
        float4 A = fv[0], Bv = fv[1];
        float fl[8] = {A.x, A.y, A.z, A.w, Bv.x, Bv.y, Bv.z, Bv.w};
        const float* gaB = ga + b * 64;
        const float* gbB = gb + b * 64;
        unsigned* row = &gl[tid * 33];
        #pragma unroll
        for (int d2 = 0; d2 < 32; d2++) {
            float h0 = b1[2 * d2], h1 = b1[2 * d2 + 1];
            #pragma unroll
            for (int c = 0; c < 8; c++) {
                h0 += W1[(2 * d2) * 8 + c] * fl[c];
                h1 += W1[(2 * d2 + 1) * 8 + c] * fl[c];
            }
            h0 = h0 * gaB[2 * d2]     + gbB[2 * d2];
            h1 = h1 * gaB[2 * d2 + 1] + gbB[2 * d2 + 1];
            float g0 = gelu_erf(h0), g1 = gelu_erf(h1);
            row[d2] = (unsigned)f2bf(g0) | ((unsigned)f2bf(g1) << 16);
        }
    }
    __syncthreads();

    // ---- phase 2: D[px][e] via MFMA (swapped operands) ----
    const int w    = tid >> 6;
    const int lane = tid & 63;
    const int quad = lane >> 4;
    const int col  = lane & 15;

    // W2 fragments (B operand): B[k][n=col] = W2[16u+col][kc*32+quad*8+j]
    s8v wfr[4][2];
    #pragma unroll
    for (int u = 0; u < 4; u++) {
        const float* wr = W2 + (size_t)(16 * u + col) * 64 + quad * 8;
        #pragma unroll
        for (int kc = 0; kc < 2; kc++) {
            const float4* w4 = (const float4*)(wr + 32 * kc);
            float4 x0 = w4[0], x1 = w4[1];
            union { unsigned short us[8]; s8v v; } cv;
            cv.us[0] = f2bf(x0.x); cv.us[1] = f2bf(x0.y);
            cv.us[2] = f2bf(x0.z); cv.us[3] = f2bf(x0.w);
            cv.us[4] = f2bf(x1.x); cv.us[5] = f2bf(x1.y);
            cv.us[6] = f2bf(x1.z); cv.us[7] = f2bf(x1.w);
            wfr[u][kc] = cv.v;
        }
    }

    // acc2[t][u]: rows px = 64w+16t+quad*4+r, col e = 16u+col; init with b2[e]
    f4v acc2[4][4];
    #pragma unroll
    for (int u = 0; u < 4; u++) {
        float bv = b2[16 * u + col];
        #pragma unroll
        for (int t = 0; t < 4; t++) {
            f4v a0; a0[0] = bv; a0[1] = bv; a0[2] = bv; a0[3] = bv;
            acc2[t][u] = a0;
        }
    }

    #pragma unroll
    for (int kc = 0; kc < 2; kc++) {
        s8v gfr[4];
        #pragma unroll
        for (int t = 0; t < 4; t++) {
            int px = 64 * w + 16 * t + col;
            const unsigned* r = &gl[px * 33 + kc * 16 + quad * 4];
            union { unsigned u4[4]; s8v v; } cv;
            cv.u4[0] = r[0]; cv.u4[1] = r[1]; cv.u4[2] = r[2]; cv.u4[3] = r[3];
            gfr[t] = cv.v;
        }
        #pragma unroll
        for (int u = 0; u < 4; u++)
            #pragma unroll
            for (int t = 0; t < 4; t++)
                acc2[t][u] = __builtin_amdgcn_mfma_f32_16x16x32_bf16(
                    gfr[t], wfr[u][kc], acc2[t][u], 0, 0, 0);
    }

    // ---- store: float4 of 4 consecutive px per (u,t) ----
    float* ob = out + (size_t)b * 64 * HW + pix0;
    #pragma unroll
    for (int u = 0; u < 4; u++) {
        float* oe = ob + (size_t)(16 * u + col) * HW + 64 * w + quad * 4;
        #pragma unroll
        for (int t = 0; t < 4; t++) {
            float4 sv = make_float4(acc2[t][u][0], acc2[t][u][1],
                                    acc2[t][u][2], acc2[t][u][3]);
            *(float4*)(oe + 16 * t) = sv;
        }
    }
}

extern "C" void kernel_launch(void* const* d_in, const int* in_sizes, int n_in,
                              void* d_out, int out_size, void* d_ws, size_t ws_size,
                              hipStream_t stream) {
    const float* x   = (const float*)d_in[0];
    const float* W1  = (const float*)d_in[1];
    const float* b1  = (const float*)d_in[2];
    const float* gnw = (const float*)d_in[3];
    const float* gnb = (const float*)d_in[4];
    const float* W2  = (const float*)d_in[5];
    const float* b2  = (const float*)d_in[6];
    float* out = (float*)d_out;

    char* ws = (char*)d_ws;
    const size_t FBYTES = (size_t)Bn * HW * 8 * sizeof(float); // 37,748,736
    float*  fbuf  = (float*)ws;
    double* stats = (double*)(ws + FBYTES);
    float*  ga    = (float*)(ws + FBYTES + 8 * 44 * sizeof(double));
    float*  gbuf  = ga + Bn * 64;

    hipMemsetAsync(stats, 0, 8 * 44 * sizeof(double), stream);
    kA<<<Bn * BLOCKS_PER_IMG, 256, 0, stream>>>(x, fbuf);
    kA2<<<72, 256, 0, stream>>>(fbuf, stats);
    kB<<<1, 512, 0, stream>>>(stats, W1, b1, gnw, gnb, ga, gbuf);
    kC2<<<Bn * BLOCKS_PER_IMG, 256, 0, stream>>>(fbuf, W1, b1, W2, b2, ga, gbuf, out);
}